// Round 1
// baseline (2257.117 us; speedup 1.0000x reference)
//
#include <hip/hip_runtime.h>
#include <stdint.h>

#define NS   2048
#define NQ   6144
#define NN   8192      // total nodes
#define IND  512
#define DM   256
#define NWAY 64
#define KNB  10
#define NSPLIT 8

// ---------- helpers ----------

// load 128 rows x 32 cols of a DM-wide row-major matrix, transposed into dst[k][m], stride 132
__device__ __forceinline__ void load_tileT(float* __restrict__ dst, const float* __restrict__ base,
                                           int r0, int kc, int t)
{
    int a  = t >> 1;            // row within tile 0..127
    int cg = (t & 1) * 16;      // col-group base within the 32-wide chunk
    const float* src = base + (size_t)(r0 + a) * DM + kc + cg;
#pragma unroll
    for (int q = 0; q < 4; ++q) {
        float4 v = *reinterpret_cast<const float4*>(src + q * 4);
        dst[(cg + q*4 + 0) * 132 + a] = v.x;
        dst[(cg + q*4 + 1) * 132 + a] = v.y;
        dst[(cg + q*4 + 2) * 132 + a] = v.z;
        dst[(cg + q*4 + 3) * 132 + a] = v.w;
    }
}

// lexicographic (value, index) insert into sorted-ascending top-10 registers
__device__ __forceinline__ void topk_insert(float v, int j, float bval[KNB], int bidx[KNB])
{
    bool better = (v < bval[KNB-1]) || (v == bval[KNB-1] && j < bidx[KNB-1]);
    if (better) {
        float cv = v; int ci = j;
#pragma unroll
        for (int q = 0; q < KNB; ++q) {
            bool sw = (cv < bval[q]) || (cv == bval[q] && ci < bidx[q]);
            if (sw) {
                float tv = bval[q]; bval[q] = cv; cv = tv;
                int   ti = bidx[q]; bidx[q] = ci; ci = ti;
            }
        }
    }
}

// ---------- 1) embed: E = concat(support,query) @ W  (8192x512x256) ----------
__global__ __launch_bounds__(256) void embed_kernel(
    const float* __restrict__ support, const float* __restrict__ query,
    const float* __restrict__ W, float* __restrict__ E)
{
    __shared__ float smemA[32 * 132];
    __shared__ float smemB[32 * 132];
    const int t  = threadIdx.x;
    const int i0 = blockIdx.x * 128;
    const int n0 = blockIdx.y * 128;
    const int tx = t & 15, ty = t >> 4;

    float acc[8][8];
#pragma unroll
    for (int m = 0; m < 8; ++m)
#pragma unroll
        for (int n = 0; n < 8; ++n) acc[m][n] = 0.f;

    for (int kc = 0; kc < IND; kc += 32) {
        // A: concat(support,query) rows i0..i0+128, transposed
        {
            int a  = t >> 1;
            int cg = (t & 1) * 16;
            int g  = i0 + a;
            const float* src = (g < NS) ? (support + (size_t)g * IND)
                                        : (query + (size_t)(g - NS) * IND);
            src += kc + cg;
#pragma unroll
            for (int q = 0; q < 4; ++q) {
                float4 v = *reinterpret_cast<const float4*>(src + q * 4);
                smemA[(cg + q*4 + 0) * 132 + a] = v.x;
                smemA[(cg + q*4 + 1) * 132 + a] = v.y;
                smemA[(cg + q*4 + 2) * 132 + a] = v.z;
                smemA[(cg + q*4 + 3) * 132 + a] = v.w;
            }
        }
        // B: W rows kc..kc+32, cols n0..n0+128, already k-major
        {
            int r  = t >> 3;            // 0..31
            int cg = (t & 7) * 16;      // 0..112
            const float* src = W + (size_t)(kc + r) * DM + n0 + cg;
#pragma unroll
            for (int q = 0; q < 4; ++q) {
                float4 v = *reinterpret_cast<const float4*>(src + q * 4);
                *reinterpret_cast<float4*>(&smemB[r * 132 + cg + q * 4]) = v;
            }
        }
        __syncthreads();
#pragma unroll
        for (int kk = 0; kk < 32; ++kk) {
            float4 a0 = *reinterpret_cast<const float4*>(&smemA[kk * 132 + ty * 8]);
            float4 a1 = *reinterpret_cast<const float4*>(&smemA[kk * 132 + ty * 8 + 4]);
            float4 b0 = *reinterpret_cast<const float4*>(&smemB[kk * 132 + tx * 8]);
            float4 b1 = *reinterpret_cast<const float4*>(&smemB[kk * 132 + tx * 8 + 4]);
            float af[8] = {a0.x, a0.y, a0.z, a0.w, a1.x, a1.y, a1.z, a1.w};
            float bf[8] = {b0.x, b0.y, b0.z, b0.w, b1.x, b1.y, b1.z, b1.w};
#pragma unroll
            for (int m = 0; m < 8; ++m)
#pragma unroll
                for (int n = 0; n < 8; ++n)
                    acc[m][n] += af[m] * bf[n];
        }
        __syncthreads();
    }
#pragma unroll
    for (int m = 0; m < 8; ++m) {
        int row = i0 + ty * 8 + m;
        float4 v0 = make_float4(acc[m][0], acc[m][1], acc[m][2], acc[m][3]);
        float4 v1 = make_float4(acc[m][4], acc[m][5], acc[m][6], acc[m][7]);
        *reinterpret_cast<float4*>(&E[(size_t)row * DM + n0 + tx * 8])     = v0;
        *reinterpret_cast<float4*>(&E[(size_t)row * DM + n0 + tx * 8 + 4]) = v1;
    }
}

// ---------- 2) row squared norms ----------
__global__ __launch_bounds__(256) void sq_kernel(const float* __restrict__ E, float* __restrict__ sq)
{
    int t = threadIdx.x;
    int w = t >> 6, l = t & 63;
    int row = blockIdx.x * 4 + w;
    const float* e = E + (size_t)row * DM;
    float s = 0.f;
#pragma unroll
    for (int q = 0; q < 4; ++q) { float x = e[l + q * 64]; s += x * x; }
#pragma unroll
    for (int off = 32; off >= 1; off >>= 1) s += __shfl_xor(s, off, 64);
    if (l == 0) sq[row] = s;
}

// ---------- 3) fused distance GEMM + streaming per-row top-10 ----------
// grid (64 row-blocks, 8 column-splits); each split covers 1024 columns
__global__ __launch_bounds__(256) void dist_topk_kernel(
    const float* __restrict__ E, const float* __restrict__ sq,
    float* __restrict__ cval, int* __restrict__ cidx)
{
    __shared__ float smem[128 * 128];       // 64 KB; aliased: A=[0,32*132), B=[32*132,64*132) during GEMM, D2 after
    float* smemA = smem;
    float* smemB = smem + 32 * 132;
    const int t     = threadIdx.x;
    const int i0    = blockIdx.x * 128;
    const int split = blockIdx.y;
    const int tx = t & 15, ty = t >> 4;

    float bval[KNB]; int bidx[KNB];
#pragma unroll
    for (int s = 0; s < KNB; ++s) { bval[s] = 3.0e38f; bidx[s] = 0x7fffffff; }

    for (int jt = 0; jt < 8; ++jt) {
        const int j0 = split * 1024 + jt * 128;
        float acc[8][8];
#pragma unroll
        for (int m = 0; m < 8; ++m)
#pragma unroll
            for (int n = 0; n < 8; ++n) acc[m][n] = 0.f;

        for (int kc = 0; kc < DM; kc += 32) {
            load_tileT(smemA, E, i0, kc, t);
            load_tileT(smemB, E, j0, kc, t);
            __syncthreads();
#pragma unroll
            for (int kk = 0; kk < 32; ++kk) {
                float4 a0 = *reinterpret_cast<const float4*>(&smemA[kk * 132 + ty * 8]);
                float4 a1 = *reinterpret_cast<const float4*>(&smemA[kk * 132 + ty * 8 + 4]);
                float4 b0 = *reinterpret_cast<const float4*>(&smemB[kk * 132 + tx * 8]);
                float4 b1 = *reinterpret_cast<const float4*>(&smemB[kk * 132 + tx * 8 + 4]);
                float af[8] = {a0.x, a0.y, a0.z, a0.w, a1.x, a1.y, a1.z, a1.w};
                float bf[8] = {b0.x, b0.y, b0.z, b0.w, b1.x, b1.y, b1.z, b1.w};
#pragma unroll
                for (int m = 0; m < 8; ++m)
#pragma unroll
                    for (int n = 0; n < 8; ++n)
                        acc[m][n] += af[m] * bf[n];
            }
            __syncthreads();
        }
        // epilogue: d2 = sq_i + sq_j - 2*dot, clamped; stage tile in LDS
        float sqr[8], sqc[8];
#pragma unroll
        for (int m = 0; m < 8; ++m) sqr[m] = sq[i0 + ty * 8 + m];
#pragma unroll
        for (int n = 0; n < 8; ++n) sqc[n] = sq[j0 + tx * 8 + n];
#pragma unroll
        for (int m = 0; m < 8; ++m)
#pragma unroll
            for (int n = 0; n < 8; ++n) {
                float d2 = sqr[m] + sqc[n] - 2.0f * acc[m][n];   // 2*acc exact (pow2) -> fma == mul+sub
                smem[(ty * 8 + m) * 128 + tx * 8 + n] = fmaxf(d2, 0.0f);
            }
        __syncthreads();
        // scan: thread t (<128) owns row t; rotated start kills bank conflicts;
        // lexicographic insert makes scan order irrelevant for tie semantics
        if (t < 128) {
            const float* rowp = &smem[t * 128];
            for (int s = 0; s < 128; ++s) {
                int col = (s + t) & 127;
                float v = rowp[col];
                topk_insert(v, j0 + col, bval, bidx);
            }
        }
        __syncthreads();
    }
    if (t < 128) {
        int row = i0 + t;
#pragma unroll
        for (int s = 0; s < KNB; ++s) {
            cval[(size_t)row * 80 + split * KNB + s] = bval[s];
            cidx[(size_t)row * 80 + split * KNB + s] = bidx[s];
        }
    }
}

// ---------- 4) merge 8 partial top-10s -> global top-10, build symmetric adjacency bitset ----------
__global__ __launch_bounds__(256) void merge_adj_kernel(
    const float* __restrict__ cval, const int* __restrict__ cidx, unsigned int* __restrict__ bits)
{
    int i = blockIdx.x * blockDim.x + threadIdx.x;
    if (i >= NN) return;
    float bval[KNB]; int bidx[KNB];
#pragma unroll
    for (int s = 0; s < KNB; ++s) { bval[s] = 3.0e38f; bidx[s] = 0x7fffffff; }
    for (int s = 0; s < NSPLIT * KNB; ++s) {
        float v = cval[(size_t)i * 80 + s];
        int   j = cidx[(size_t)i * 80 + s];
        topk_insert(v, j, bval, bidx);
    }
#pragma unroll
    for (int s = 0; s < KNB; ++s) {
        int j = bidx[s];
        atomicOr(&bits[(size_t)i * 256 + (j >> 5)], 1u << (j & 31));
        atomicOr(&bits[(size_t)j * 256 + (i >> 5)], 1u << (i & 31));
    }
}

// ---------- 5) label init ----------
__global__ __launch_bounds__(256) void labels_init_kernel(const int* __restrict__ slab, float* __restrict__ la)
{
    int tid = blockIdx.x * blockDim.x + threadIdx.x;   // NN*64 threads
    int i = tid >> 6, c = tid & 63;
    float v = 0.f;
    if (i < NS) v = (slab[i] == c) ? 1.f : 0.f;
    la[tid] = v;
}

// ---------- 6) one propagation step: lout[i] = (1/deg_i) * sum_{j in N(i)} lin[j] ----------
__global__ __launch_bounds__(64) void prop_kernel(
    const unsigned int* __restrict__ bits, const float* __restrict__ lin, float* __restrict__ lout)
{
    int i = blockIdx.x;
    int c = threadIdx.x;
    const unsigned int* row = bits + (size_t)i * 256;
    int deg = 0;
    for (int w = 0; w < 256; ++w) deg += __popc(row[w]);
    float tinv = 1.0f / (float)deg;                    // deg >= 1 (self-loop always present)
    float acc = 0.f;
    for (int w = 0; w < 256; ++w) {
        unsigned int m = row[w];
        while (m) {
            int b = __ffs(m) - 1;
            m &= m - 1;
            int j = w * 32 + b;
            acc += __fmul_rn(tinv, lin[(size_t)j * 64 + c]);   // separate mul like reference's trans entries
        }
    }
    lout[(size_t)i * 64 + c] = acc;
}

// ---------- 7) argmax (first-index tie-break) -> one-hot ----------
__global__ __launch_bounds__(64) void argmax_kernel(const float* __restrict__ labels, float* __restrict__ out)
{
    int q = blockIdx.x;         // 0..NQ-1
    int c = threadIdx.x;
    float bv = labels[(size_t)(NS + q) * 64 + c];
    int   bi = c;
#pragma unroll
    for (int off = 32; off >= 1; off >>= 1) {
        float ov = __shfl_xor(bv, off, 64);
        int   oi = __shfl_xor(bi, off, 64);
        if (ov > bv || (ov == bv && oi < bi)) { bv = ov; bi = oi; }
    }
    out[(size_t)q * 64 + c] = (c == bi) ? 1.0f : 0.0f;
}

// ---------- launch ----------
extern "C" void kernel_launch(void* const* d_in, const int* in_sizes, int n_in,
                              void* d_out, int out_size, void* d_ws, size_t ws_size,
                              hipStream_t stream)
{
    const float* support = (const float*)d_in[0];
    const float* query   = (const float*)d_in[1];
    const int*   slab    = (const int*)d_in[2];
    const float* W       = (const float*)d_in[3];
    float* out = (float*)d_out;
    char*  ws  = (char*)d_ws;

    // workspace layout (phase-aliased):
    //   [0, 8M)        E (fp32 8192x256)  -> later reused as adjacency bitset (8192x256 u32, same 8 MB)
    //   [8M, +32K)     sq
    //   [8.03M, +2.5M) cand vals  -> later reused as labels_a
    //   [10.5M, +2.5M) cand idxs  -> later reused as labels_b
    float*        E    = (float*)(ws + 0);
    unsigned int* bits = (unsigned int*)(ws + 0);
    float*        sq   = (float*)(ws + 8388608);
    float*        cval = (float*)(ws + 8421376);
    int*          cidx = (int*)  (ws + 11042816);
    float*        la   = (float*)(ws + 8421376);    // aliases cval (dead after merge)
    float*        lb   = (float*)(ws + 11042816);   // aliases cidx (dead after merge)

    embed_kernel<<<dim3(64, 2), 256, 0, stream>>>(support, query, W, E);
    sq_kernel<<<2048, 256, 0, stream>>>(E, sq);
    dist_topk_kernel<<<dim3(64, NSPLIT), 256, 0, stream>>>(E, sq, cval, cidx);
    hipMemsetAsync(bits, 0, (size_t)NN * 256 * sizeof(unsigned int), stream);   // E dead now
    merge_adj_kernel<<<NN / 256, 256, 0, stream>>>(cval, cidx, bits);
    labels_init_kernel<<<(NN * 64) / 256, 256, 0, stream>>>(slab, la);          // cval dead now
    prop_kernel<<<NN, 64, 0, stream>>>(bits, la, lb);
    prop_kernel<<<NN, 64, 0, stream>>>(bits, lb, la);
    prop_kernel<<<NN, 64, 0, stream>>>(bits, la, lb);
    argmax_kernel<<<NQ, 64, 0, stream>>>(lb, out);
}

// Round 2
// 2197.991 us; speedup vs baseline: 1.0269x; 1.0269x over previous
//
#include <hip/hip_runtime.h>
#include <stdint.h>

#define NS   2048
#define NQ   6144
#define NN   8192      // total nodes
#define IND  512
#define DM   256
#define NWAY 64
#define KNB  10

// ---------- helpers ----------

// load 128 rows x 32 cols of a DM-wide row-major matrix, transposed into dst[k][m], stride 132
__device__ __forceinline__ void load_tileT(float* __restrict__ dst, const float* __restrict__ base,
                                           int r0, int kc, int t)
{
    int a  = t >> 1;            // row within tile 0..127
    int cg = (t & 1) * 16;      // col-group base within the 32-wide chunk
    const float* src = base + (size_t)(r0 + a) * DM + kc + cg;
#pragma unroll
    for (int q = 0; q < 4; ++q) {
        float4 v = *reinterpret_cast<const float4*>(src + q * 4);
        dst[(cg + q*4 + 0) * 132 + a] = v.x;
        dst[(cg + q*4 + 1) * 132 + a] = v.y;
        dst[(cg + q*4 + 2) * 132 + a] = v.z;
        dst[(cg + q*4 + 3) * 132 + a] = v.w;
    }
}

// lexicographic (value, index) insert into sorted-ascending top-10 registers
__device__ __forceinline__ void topk_insert(float v, int j, float bval[KNB], int bidx[KNB])
{
    bool better = (v < bval[KNB-1]) || (v == bval[KNB-1] && j < bidx[KNB-1]);
    if (better) {
        float cv = v; int ci = j;
#pragma unroll
        for (int q = 0; q < KNB; ++q) {
            bool sw = (cv < bval[q]) || (cv == bval[q] && ci < bidx[q]);
            if (sw) {
                float tv = bval[q]; bval[q] = cv; cv = tv;
                int   ti = bidx[q]; bidx[q] = ci; ci = ti;
            }
        }
    }
}

// ---------- 1) embed: E = concat(support,query) @ W  (8192x512x256), 64x128 tiles ----------
__global__ __launch_bounds__(256) void embed_kernel(
    const float* __restrict__ support, const float* __restrict__ query,
    const float* __restrict__ W, float* __restrict__ E)
{
    __shared__ float smemA[32 * 68];     // A^T: [k][m], 64 rows
    __shared__ float smemB[32 * 132];    // B:   [k][n], 128 cols
    const int t  = threadIdx.x;
    const int i0 = blockIdx.x * 64;
    const int n0 = blockIdx.y * 128;
    const int tx = t & 15, ty = t >> 4;

    float acc[4][8];
#pragma unroll
    for (int m = 0; m < 4; ++m)
#pragma unroll
        for (int n = 0; n < 8; ++n) acc[m][n] = 0.f;

    for (int kc = 0; kc < IND; kc += 32) {
        // A: rows i0..i0+64 of concat(support,query), cols kc..kc+32, transposed
        {
            int a  = t >> 2;            // 0..63
            int cg = (t & 3) * 8;       // 0,8,16,24
            int g  = i0 + a;
            const float* src = (g < NS) ? (support + (size_t)g * IND)
                                        : (query + (size_t)(g - NS) * IND);
            src += kc + cg;
#pragma unroll
            for (int q = 0; q < 2; ++q) {
                float4 v = *reinterpret_cast<const float4*>(src + q * 4);
                smemA[(cg + q*4 + 0) * 68 + a] = v.x;
                smemA[(cg + q*4 + 1) * 68 + a] = v.y;
                smemA[(cg + q*4 + 2) * 68 + a] = v.z;
                smemA[(cg + q*4 + 3) * 68 + a] = v.w;
            }
        }
        // B: W rows kc..kc+32, cols n0..n0+128 (k-major already)
        {
            int r  = t >> 3;            // 0..31
            int cg = (t & 7) * 16;      // 0..112
            const float* src = W + (size_t)(kc + r) * DM + n0 + cg;
#pragma unroll
            for (int q = 0; q < 4; ++q) {
                float4 v = *reinterpret_cast<const float4*>(src + q * 4);
                *reinterpret_cast<float4*>(&smemB[r * 132 + cg + q * 4]) = v;
            }
        }
        __syncthreads();
#pragma unroll
        for (int kk = 0; kk < 32; ++kk) {
            float4 a0 = *reinterpret_cast<const float4*>(&smemA[kk * 68 + ty * 4]);
            float4 b0 = *reinterpret_cast<const float4*>(&smemB[kk * 132 + tx * 8]);
            float4 b1 = *reinterpret_cast<const float4*>(&smemB[kk * 132 + tx * 8 + 4]);
            float af[4] = {a0.x, a0.y, a0.z, a0.w};
            float bf[8] = {b0.x, b0.y, b0.z, b0.w, b1.x, b1.y, b1.z, b1.w};
#pragma unroll
            for (int m = 0; m < 4; ++m)
#pragma unroll
                for (int n = 0; n < 8; ++n)
                    acc[m][n] += af[m] * bf[n];
        }
        __syncthreads();
    }
#pragma unroll
    for (int m = 0; m < 4; ++m) {
        int row = i0 + ty * 4 + m;
        float4 v0 = make_float4(acc[m][0], acc[m][1], acc[m][2], acc[m][3]);
        float4 v1 = make_float4(acc[m][4], acc[m][5], acc[m][6], acc[m][7]);
        *reinterpret_cast<float4*>(&E[(size_t)row * DM + n0 + tx * 8])     = v0;
        *reinterpret_cast<float4*>(&E[(size_t)row * DM + n0 + tx * 8 + 4]) = v1;
    }
}

// ---------- 2) row squared norms ----------
__global__ __launch_bounds__(256) void sq_kernel(const float* __restrict__ E, float* __restrict__ sq)
{
    int t = threadIdx.x;
    int w = t >> 6, l = t & 63;
    int row = blockIdx.x * 4 + w;
    const float* e = E + (size_t)row * DM;
    float s = 0.f;
#pragma unroll
    for (int q = 0; q < 4; ++q) { float x = e[l + q * 64]; s += x * x; }
#pragma unroll
    for (int off = 32; off >= 1; off >>= 1) s += __shfl_xor(s, off, 64);
    if (l == 0) sq[row] = s;
}

// ---------- 3) fused distance GEMM + streaming per-row top-10 ----------
// grid (64 row-blocks, nsplit column-splits)
__global__ __launch_bounds__(256, 4) void dist_topk_kernel(
    const float* __restrict__ E, const float* __restrict__ sq,
    float* __restrict__ cval, int* __restrict__ cidx,
    int cols_per_split, int njt, int cstride)
{
    // 33792 B total. GEMM phase: A=[0,32*132), B=[32*132,64*132).
    // Epilogue: same buffer re-used as 64x128 half-tile D2 staging (32768 B).
    __shared__ float smem[2 * 32 * 132];
    float* smemA = smem;
    float* smemB = smem + 32 * 132;
    const int t     = threadIdx.x;
    const int i0    = blockIdx.x * 128;
    const int split = blockIdx.y;
    const int tx = t & 15, ty = t >> 4;

    float bval[KNB]; int bidx[KNB];
#pragma unroll
    for (int s = 0; s < KNB; ++s) { bval[s] = 3.0e38f; bidx[s] = 0x7fffffff; }

    for (int jt = 0; jt < njt; ++jt) {
        const int j0 = split * cols_per_split + jt * 128;
        float acc[8][8];
#pragma unroll
        for (int m = 0; m < 8; ++m)
#pragma unroll
            for (int n = 0; n < 8; ++n) acc[m][n] = 0.f;

        for (int kc = 0; kc < DM; kc += 32) {
            load_tileT(smemA, E, i0, kc, t);
            load_tileT(smemB, E, j0, kc, t);
            __syncthreads();
#pragma unroll
            for (int kk = 0; kk < 32; ++kk) {
                float4 a0 = *reinterpret_cast<const float4*>(&smemA[kk * 132 + ty * 8]);
                float4 a1 = *reinterpret_cast<const float4*>(&smemA[kk * 132 + ty * 8 + 4]);
                float4 b0 = *reinterpret_cast<const float4*>(&smemB[kk * 132 + tx * 8]);
                float4 b1 = *reinterpret_cast<const float4*>(&smemB[kk * 132 + tx * 8 + 4]);
                float af[8] = {a0.x, a0.y, a0.z, a0.w, a1.x, a1.y, a1.z, a1.w};
                float bf[8] = {b0.x, b0.y, b0.z, b0.w, b1.x, b1.y, b1.z, b1.w};
#pragma unroll
                for (int m = 0; m < 8; ++m)
#pragma unroll
                    for (int n = 0; n < 8; ++n)
                        acc[m][n] += af[m] * bf[n];
            }
            __syncthreads();
        }
        // epilogue: d2 = sq_i + sq_j - 2*dot, clamped; two-phase 64x128 staging.
        // Store permutation: element (r, c) with c = tx*8+n lands at physical col
        //   q = tx*8 + ((n + (tx>>2) + 4*((r>>3)&3)) & 7)
        // -> each scalar-store instruction hits 32 banks at 2-way (free).
        float sqc[8];
#pragma unroll
        for (int n = 0; n < 8; ++n) sqc[n] = sq[j0 + tx * 8 + n];

        // ---- phase 0: rows 0..63 (threads with ty < 8 store) ----
        if (ty < 8) {
#pragma unroll
            for (int m = 0; m < 8; ++m) {
                int r = ty * 8 + m;
                float sr = sq[i0 + r];
                int swz = (ty & 3) * 4;
#pragma unroll
                for (int n = 0; n < 8; ++n) {
                    float d2 = sr + sqc[n] - 2.0f * acc[m][n];
                    int p = (n + (tx >> 2) + swz) & 7;
                    smem[r * 128 + tx * 8 + p] = fmaxf(d2, 0.0f);
                }
            }
        }
        __syncthreads();
        if (t < 64) {
            const float* rowp = &smem[t * 128];
            int swz = (t >> 3) & 3;
            for (int s = 0; s < 128; ++s) {
                int pp = (s + t) & 127;
                float v = rowp[pp];
                int g = pp >> 3, pe = pp & 7;
                int c = g * 8 + ((pe - (g >> 2) - 4 * swz) & 7);
                topk_insert(v, j0 + c, bval, bidx);
            }
        }
        __syncthreads();
        // ---- phase 1: rows 64..127 (threads with ty >= 8 store) ----
        if (ty >= 8) {
#pragma unroll
            for (int m = 0; m < 8; ++m) {
                int r = ty * 8 + m;           // 64..127
                float sr = sq[i0 + r];
                int swz = (ty & 3) * 4;
#pragma unroll
                for (int n = 0; n < 8; ++n) {
                    float d2 = sr + sqc[n] - 2.0f * acc[m][n];
                    int p = (n + (tx >> 2) + swz) & 7;
                    smem[(r - 64) * 128 + tx * 8 + p] = fmaxf(d2, 0.0f);
                }
            }
        }
        __syncthreads();
        if (t >= 64 && t < 128) {
            const float* rowp = &smem[(t - 64) * 128];
            int swz = (t >> 3) & 3;
            for (int s = 0; s < 128; ++s) {
                int pp = (s + t) & 127;
                float v = rowp[pp];
                int g = pp >> 3, pe = pp & 7;
                int c = g * 8 + ((pe - (g >> 2) - 4 * swz) & 7);
                topk_insert(v, j0 + c, bval, bidx);
            }
        }
        __syncthreads();
    }
    if (t < 128) {
        int row = i0 + t;
        size_t base = (size_t)row * cstride + split * KNB;
#pragma unroll
        for (int s = 0; s < KNB; ++s) {
            cval[base + s] = bval[s];
            cidx[base + s] = bidx[s];
        }
    }
}

// ---------- 4) merge partial top-10s -> global top-10, build symmetric adjacency bitset ----------
__global__ __launch_bounds__(256) void merge_adj_kernel(
    const float* __restrict__ cval, const int* __restrict__ cidx,
    unsigned int* __restrict__ bits, int ncand, int cstride)
{
    int i = blockIdx.x * blockDim.x + threadIdx.x;
    if (i >= NN) return;
    float bval[KNB]; int bidx[KNB];
#pragma unroll
    for (int s = 0; s < KNB; ++s) { bval[s] = 3.0e38f; bidx[s] = 0x7fffffff; }
    for (int s = 0; s < ncand; ++s) {
        float v = cval[(size_t)i * cstride + s];
        int   j = cidx[(size_t)i * cstride + s];
        topk_insert(v, j, bval, bidx);
    }
#pragma unroll
    for (int s = 0; s < KNB; ++s) {
        int j = bidx[s];
        atomicOr(&bits[(size_t)i * 256 + (j >> 5)], 1u << (j & 31));
        atomicOr(&bits[(size_t)j * 256 + (i >> 5)], 1u << (i & 31));
    }
}

// ---------- 5) label init ----------
__global__ __launch_bounds__(256) void labels_init_kernel(const int* __restrict__ slab, float* __restrict__ la)
{
    int tid = blockIdx.x * blockDim.x + threadIdx.x;   // NN*64 threads
    int i = tid >> 6, c = tid & 63;
    float v = 0.f;
    if (i < NS) v = (slab[i] == c) ? 1.f : 0.f;
    la[tid] = v;
}

// ---------- 6) one propagation step: lout[i] = (1/deg_i) * sum_{j in N(i)} lin[j] ----------
// 4 nodes per 256-thread block (one wave per node); per-wave body identical to the
// round-1 version (numerics and j-order preserved — passed absmax 0).
__global__ __launch_bounds__(256) void prop_kernel(
    const unsigned int* __restrict__ bits, const float* __restrict__ lin, float* __restrict__ lout)
{
    int i = blockIdx.x * 4 + (threadIdx.x >> 6);
    int c = threadIdx.x & 63;
    const unsigned int* row = bits + (size_t)i * 256;
    int deg = 0;
    for (int w = 0; w < 256; ++w) deg += __popc(row[w]);
    float tinv = 1.0f / (float)deg;                    // deg >= 1 (self-loop always present)
    float acc = 0.f;
    for (int w = 0; w < 256; ++w) {
        unsigned int m = row[w];
        while (m) {
            int b = __ffs(m) - 1;
            m &= m - 1;
            int j = w * 32 + b;
            acc += __fmul_rn(tinv, lin[(size_t)j * 64 + c]);
        }
    }
    lout[(size_t)i * 64 + c] = acc;
}

// ---------- 7) argmax (first-index tie-break) -> one-hot ----------
__global__ __launch_bounds__(256) void argmax_kernel(const float* __restrict__ labels, float* __restrict__ out)
{
    int q = blockIdx.x * 4 + (threadIdx.x >> 6);   // 0..NQ-1
    int c = threadIdx.x & 63;
    float bv = labels[(size_t)(NS + q) * 64 + c];
    int   bi = c;
#pragma unroll
    for (int off = 32; off >= 1; off >>= 1) {
        float ov = __shfl_xor(bv, off, 64);
        int   oi = __shfl_xor(bi, off, 64);
        if (ov > bv || (ov == bv && oi < bi)) { bv = ov; bi = oi; }
    }
    out[(size_t)q * 64 + c] = (c == bi) ? 1.0f : 0.0f;
}

// ---------- launch ----------
extern "C" void kernel_launch(void* const* d_in, const int* in_sizes, int n_in,
                              void* d_out, int out_size, void* d_ws, size_t ws_size,
                              hipStream_t stream)
{
    const float* support = (const float*)d_in[0];
    const float* query   = (const float*)d_in[1];
    const int*   slab    = (const int*)d_in[2];
    const float* W       = (const float*)d_in[3];
    float* out = (float*)d_out;
    char*  ws  = (char*)d_ws;

    // workspace layout (phase-aliased):
    //   [0, 8M)     E (fp32 8192x256)  -> later reused as adjacency bitset (8192x256 u32)
    //   [8M, +32K)  sq
    //   then cval / cidx (size depends on nsplit)  -> later reused as labels_a / labels_b
    const size_t candOff = 8388608 + 32768;            // 8,421,376
    // choose split count by available workspace: 16 splits need 2 * 8192*160*4 B
    int nsplit = 8;
    if (ws_size >= candOff + 2ull * (size_t)NN * 16 * KNB * 4 + 16) nsplit = 16;
    const int cstride = nsplit * KNB;
    const int cols_per_split = NN / nsplit;
    const int njt = cols_per_split / 128;
    const size_t candBytes = (size_t)NN * cstride * 4;

    float*        E    = (float*)(ws + 0);
    unsigned int* bits = (unsigned int*)(ws + 0);
    float*        sq   = (float*)(ws + 8388608);
    float*        cval = (float*)(ws + candOff);
    int*          cidx = (int*)  (ws + candOff + candBytes);
    float*        la   = (float*)(ws + candOff);               // aliases cval (dead after merge)
    float*        lb   = (float*)(ws + candOff + candBytes);   // aliases cidx (dead after merge)

    embed_kernel<<<dim3(128, 2), 256, 0, stream>>>(support, query, W, E);
    sq_kernel<<<2048, 256, 0, stream>>>(E, sq);
    dist_topk_kernel<<<dim3(64, nsplit), 256, 0, stream>>>(E, sq, cval, cidx,
                                                           cols_per_split, njt, cstride);
    hipMemsetAsync(bits, 0, (size_t)NN * 256 * sizeof(unsigned int), stream);   // E dead now
    merge_adj_kernel<<<NN / 256, 256, 0, stream>>>(cval, cidx, bits, cstride, cstride);
    labels_init_kernel<<<(NN * 64) / 256, 256, 0, stream>>>(slab, la);          // cval dead now
    prop_kernel<<<NN / 4, 256, 0, stream>>>(bits, la, lb);
    prop_kernel<<<NN / 4, 256, 0, stream>>>(bits, lb, la);
    prop_kernel<<<NN / 4, 256, 0, stream>>>(bits, la, lb);
    argmax_kernel<<<NQ / 4, 256, 0, stream>>>(lb, out);
}